// Round 7
// baseline (1251.582 us; speedup 1.0000x reference)
//
#include <hip/hip_runtime.h>

#define NN    100000
#define FIN   64
#define HID   32
#define NCLS  10
#define CBW   128                   // destinations per col-bucket
#define NBC   782                   // ceil(NN/128)
#define RBW   256                   // rows per row-bucket
#define NBR   391                   // ceil(NN/256)
#define HB    512                   // blocks in hist/bucket passes

__device__ __forceinline__ unsigned short f2bf(float x) {
    unsigned u = __float_as_uint(x);
    u = (u + 0x7FFFu + ((u >> 16) & 1u)) >> 16;   // round-to-nearest-even
    return (unsigned short)u;
}
__device__ __forceinline__ float bf2f(unsigned short s) {
    return __uint_as_float(((unsigned)s) << 16);
}

// ---------------------------------------------------------------------------
// hist2: per-block LDS histograms of col-buckets (c>>7) and row-buckets (r>>8).
// ghc/ghr layout [bucket][block]. No global atomics.
// ---------------------------------------------------------------------------
__global__ __launch_bounds__(256) void hist2_kernel(
        const int* __restrict__ row, const int* __restrict__ col,
        int* __restrict__ ghc, int* __restrict__ ghr, int E, int chunk) {
    __shared__ int lhc[NBC], lhr[NBR];
    for (int t = threadIdx.x; t < NBC; t += 256) lhc[t] = 0;
    for (int t = threadIdx.x; t < NBR; t += 256) lhr[t] = 0;
    __syncthreads();
    int k = blockIdx.x;
    int base = k * chunk;
    int lim = base + chunk; if (lim > E) lim = E;
    for (int e = base + threadIdx.x; e < lim; e += 256) {
        int r = row[e], c = col[e];
        if (r != c) {
            atomicAdd(&lhc[c >> 7], 1);
            atomicAdd(&lhr[r >> 8], 1);
        }
    }
    __syncthreads();
    for (int t = threadIdx.x; t < NBC; t += 256) ghc[t * HB + k] = lhc[t];
    for (int t = threadIdx.x; t < NBR; t += 256) ghr[t * HB + k] = lhr[t];
}

// ---------------------------------------------------------------------------
// coffs: per-bucket exclusive scan over the HB block-columns (in place) and
// per-bucket totals. Blocks 0..NBC-1 do ghc; blocks < NBR also do ghr.
// ---------------------------------------------------------------------------
__global__ __launch_bounds__(512) void coffs_kernel(
        int* __restrict__ ghc, int* __restrict__ ghr,
        int* __restrict__ ctot, int* __restrict__ rtot) {
    __shared__ int sh[HB];
    int b = blockIdx.x, t = threadIdx.x;
    int v = ghc[b * HB + t];
    sh[t] = v;
    __syncthreads();
    for (int off = 1; off < HB; off <<= 1) {
        int u = (t >= off) ? sh[t - off] : 0;
        __syncthreads(); sh[t] += u; __syncthreads();
    }
    ghc[b * HB + t] = sh[t] - v;
    if (t == HB - 1) ctot[b] = sh[t];
    if (b < NBR) {
        __syncthreads();
        int w = ghr[b * HB + t];
        sh[t] = w;
        __syncthreads();
        for (int off = 1; off < HB; off <<= 1) {
            int u = (t >= off) ? sh[t - off] : 0;
            __syncthreads(); sh[t] += u; __syncthreads();
        }
        ghr[b * HB + t] = sh[t] - w;
        if (t == HB - 1) rtot[b] = sh[t];
    }
}

// ---------------------------------------------------------------------------
// bscan: exclusive scan of bucket totals for both keys.
// ---------------------------------------------------------------------------
__global__ __launch_bounds__(1024) void bscan_kernel(
        const int* __restrict__ ctot, const int* __restrict__ rtot,
        int* __restrict__ cbptr, int* __restrict__ rbptr) {
    __shared__ int sh[1024];
    int t = threadIdx.x;
    int v = (t < NBC) ? ctot[t] : 0;
    sh[t] = v;
    __syncthreads();
    for (int off = 1; off < 1024; off <<= 1) {
        int u = (t >= off) ? sh[t - off] : 0;
        __syncthreads(); sh[t] += u; __syncthreads();
    }
    if (t < NBC) cbptr[t] = sh[t] - v;
    if (t == NBC - 1) cbptr[NBC] = sh[t];
    __syncthreads();
    int w = (t < NBR) ? rtot[t] : 0;
    sh[t] = w;
    __syncthreads();
    for (int off = 1; off < 1024; off <<= 1) {
        int u = (t >= off) ? sh[t - off] : 0;
        __syncthreads(); sh[t] += u; __syncthreads();
    }
    if (t < NBR) rbptr[t] = sh[t] - w;
    if (t == NBR - 1) rbptr[NBR] = sh[t];
}

// ---------------------------------------------------------------------------
// bucket2: deterministic bucketing (LDS cursors seeded from scans). Writes
// packed (r<<7)|(c&127) by col-bucket and byte (r&255) by row-bucket.
// ---------------------------------------------------------------------------
__global__ __launch_bounds__(256) void bucket2_kernel(
        const int* __restrict__ row, const int* __restrict__ col,
        const int* __restrict__ ghc, const int* __restrict__ ghr,
        const int* __restrict__ cbptr, const int* __restrict__ rbptr,
        int* __restrict__ pk, unsigned char* __restrict__ rkb,
        int E, int chunk) {
    __shared__ int lcc[NBC], lcr[NBR];
    int k = blockIdx.x;
    for (int t = threadIdx.x; t < NBC; t += 256) lcc[t] = cbptr[t] + ghc[t * HB + k];
    for (int t = threadIdx.x; t < NBR; t += 256) lcr[t] = rbptr[t] + ghr[t * HB + k];
    __syncthreads();
    int base = k * chunk;
    int lim = base + chunk; if (lim > E) lim = E;
    for (int e = base + threadIdx.x; e < lim; e += 256) {
        int r = row[e], c = col[e];
        if (r != c) {
            int pc = atomicAdd(&lcc[c >> 7], 1);
            pk[pc] = (r << 7) | (c & 127);
            int pr = atomicAdd(&lcr[r >> 8], 1);
            rkb[pr] = (unsigned char)(r & 255);
        }
    }
}

// ---------------------------------------------------------------------------
// countR: per-row-bucket histogram of the byte stream -> dis[] directly.
// ---------------------------------------------------------------------------
__global__ __launch_bounds__(256) void countR_kernel(
        const unsigned char* __restrict__ rkb, const int* __restrict__ rbptr,
        float* __restrict__ dis) {
    __shared__ int cnt[RBW];
    int b = blockIdx.x, t = threadIdx.x;
    cnt[t] = 0;
    __syncthreads();
    int s = rbptr[b], e = rbptr[b + 1];
    for (int i = s + t; i < e; i += 256) atomicAdd(&cnt[rkb[i]], 1);
    __syncthreads();
    int d = (b << 8) + t;
    if (d < NN) {
        int c = cnt[t];
        dis[d] = c > 0 ? rsqrtf((float)c) : 0.f;
    }
}

// ---------------------------------------------------------------------------
// mm1: xw0 = x @ W0_1 + b1 (fp32)  and  y1b = bf16(dis[n] * (x @ W1_1))
// ---------------------------------------------------------------------------
__global__ __launch_bounds__(256) void mm1_kernel(
        const float* __restrict__ x, const float* __restrict__ dis,
        const float* __restrict__ W0, const float* __restrict__ W1,
        const float* __restrict__ b1, float* __restrict__ xw0,
        unsigned* __restrict__ y1b) {
    int n = blockIdx.x * 256 + threadIdx.x;
    if (n >= NN) return;
    float acc0[HID], acc1[HID];
#pragma unroll
    for (int j = 0; j < HID; ++j) { acc0[j] = b1[j]; acc1[j] = 0.f; }
    const float4* xr = (const float4*)(x + (size_t)n * FIN);
    for (int k4 = 0; k4 < FIN / 4; ++k4) {
        float4 xv = xr[k4];
        float xs[4] = {xv.x, xv.y, xv.z, xv.w};
#pragma unroll
        for (int kk = 0; kk < 4; ++kk) {
            const float* w0r = W0 + (k4 * 4 + kk) * HID;
            const float* w1r = W1 + (k4 * 4 + kk) * HID;
#pragma unroll
            for (int j = 0; j < HID; ++j) {
                acc0[j] += xs[kk] * w0r[j];
                acc1[j] += xs[kk] * w1r[j];
            }
        }
    }
    float dn = dis[n];
    float4* d0 = (float4*)(xw0 + (size_t)n * HID);
#pragma unroll
    for (int j4 = 0; j4 < HID / 4; ++j4)
        d0[j4] = make_float4(acc0[j4*4], acc0[j4*4+1], acc0[j4*4+2], acc0[j4*4+3]);
    unsigned pw[16];
#pragma unroll
    for (int j2 = 0; j2 < 16; ++j2)
        pw[j2] = (unsigned)f2bf(dn * acc1[2*j2]) | ((unsigned)f2bf(dn * acc1[2*j2+1]) << 16);
    uint4* yd = (uint4*)(y1b + (size_t)n * 16);
#pragma unroll
    for (int q = 0; q < 4; ++q)
        yd[q] = make_uint4(pw[q*4], pw[q*4+1], pw[q*4+2], pw[q*4+3]);
}

// ---------------------------------------------------------------------------
// fgH: fused per-col-bucket gather + layer1 epilogue.
// h[c] = relu(xw0[c] - dis[c] * sum_{r in N(c)} y1[r]); LDS fp32 accumulate.
// ---------------------------------------------------------------------------
__global__ __launch_bounds__(256) void fgH_kernel(
        const int* __restrict__ pk, const int* __restrict__ cbptr,
        const unsigned short* __restrict__ y1b, const float* __restrict__ xw0,
        const float* __restrict__ dis, float* __restrict__ h) {
    __shared__ float tile[CBW * 33];
    int tid = threadIdx.x;
    for (int q = tid; q < CBW * 33; q += 256) tile[q] = 0.f;
    int b = blockIdx.x;
    int start = cbptr[b], end = cbptr[b + 1];
    int slot = tid >> 5;          // 8 half-wave edge slots
    int f = tid & 31;
    __syncthreads();
    int i = start + slot;
    for (; i + 24 < end; i += 32) {
        int p0 = pk[i], p1 = pk[i + 8], p2 = pk[i + 16], p3 = pk[i + 24];
        float v0 = bf2f(y1b[(size_t)(p0 >> 7) * HID + f]);
        float v1 = bf2f(y1b[(size_t)(p1 >> 7) * HID + f]);
        float v2 = bf2f(y1b[(size_t)(p2 >> 7) * HID + f]);
        float v3 = bf2f(y1b[(size_t)(p3 >> 7) * HID + f]);
        atomicAdd(&tile[(p0 & 127) * 33 + f], v0);
        atomicAdd(&tile[(p1 & 127) * 33 + f], v1);
        atomicAdd(&tile[(p2 & 127) * 33 + f], v2);
        atomicAdd(&tile[(p3 & 127) * 33 + f], v3);
    }
    for (; i < end; i += 8) {
        int p = pk[i];
        atomicAdd(&tile[(p & 127) * 33 + f], bf2f(y1b[(size_t)(p >> 7) * HID + f]));
    }
    __syncthreads();
    int d = tid >> 1;
    int g = b * CBW + d;
    if (g < NN) {
        int hf = (tid & 1) * 16;
        float dc = dis[g];
        const float4* xs = (const float4*)(xw0 + (size_t)g * HID + hf);
        float4* hd = (float4*)(h + (size_t)g * HID + hf);
        const float* tr = &tile[d * 33 + hf];
#pragma unroll
        for (int q4 = 0; q4 < 4; ++q4) {
            float4 xv = xs[q4];
            float4 o;
            o.x = fmaxf(xv.x - dc * tr[q4*4 + 0], 0.f);
            o.y = fmaxf(xv.y - dc * tr[q4*4 + 1], 0.f);
            o.z = fmaxf(xv.z - dc * tr[q4*4 + 2], 0.f);
            o.w = fmaxf(xv.w - dc * tr[q4*4 + 3], 0.f);
            hd[q4] = o;
        }
    }
}

// ---------------------------------------------------------------------------
// mm2: hw0 = h @ W0_2 + b2 (fp32, [NN,10])  and  y2b = bf16(dis*(h @ W1_2))
// padded to 16 halfwords.
// ---------------------------------------------------------------------------
__global__ __launch_bounds__(256) void mm2_kernel(
        const float* __restrict__ h, const float* __restrict__ dis,
        const float* __restrict__ W0, const float* __restrict__ W1,
        const float* __restrict__ b2, float* __restrict__ hw0,
        unsigned* __restrict__ y2b) {
    int n = blockIdx.x * 256 + threadIdx.x;
    if (n >= NN) return;
    float acc0[NCLS], acc1[NCLS];
#pragma unroll
    for (int j = 0; j < NCLS; ++j) { acc0[j] = b2[j]; acc1[j] = 0.f; }
    const float4* hr = (const float4*)(h + (size_t)n * HID);
#pragma unroll
    for (int k4 = 0; k4 < HID / 4; ++k4) {
        float4 hv = hr[k4];
        float hs[4] = {hv.x, hv.y, hv.z, hv.w};
#pragma unroll
        for (int kk = 0; kk < 4; ++kk) {
            const float* w0r = W0 + (k4 * 4 + kk) * NCLS;
            const float* w1r = W1 + (k4 * 4 + kk) * NCLS;
#pragma unroll
            for (int j = 0; j < NCLS; ++j) {
                acc0[j] += hs[kk] * w0r[j];
                acc1[j] += hs[kk] * w1r[j];
            }
        }
    }
    float dn = dis[n];
    float* hd = hw0 + (size_t)n * NCLS;
#pragma unroll
    for (int j = 0; j < NCLS; ++j) hd[j] = acc0[j];
    float v[16];
#pragma unroll
    for (int j = 0; j < NCLS; ++j) v[j] = dn * acc1[j];
#pragma unroll
    for (int j = NCLS; j < 16; ++j) v[j] = 0.f;
    unsigned pw[8];
#pragma unroll
    for (int j2 = 0; j2 < 8; ++j2)
        pw[j2] = (unsigned)f2bf(v[2*j2]) | ((unsigned)f2bf(v[2*j2+1]) << 16);
    uint4* yd = (uint4*)(y2b + (size_t)n * 8);
    yd[0] = make_uint4(pw[0], pw[1], pw[2], pw[3]);
    yd[1] = make_uint4(pw[4], pw[5], pw[6], pw[7]);
}

// ---------------------------------------------------------------------------
// fgO: fused per-col-bucket gather + layer2 epilogue (log_softmax), staged
// coalesced flush of the [128][10] output.
// ---------------------------------------------------------------------------
__global__ __launch_bounds__(256) void fgO_kernel(
        const int* __restrict__ pk, const int* __restrict__ cbptr,
        const unsigned short* __restrict__ y2b, const float* __restrict__ hw0,
        const float* __restrict__ dis, float* __restrict__ out) {
    __shared__ float tile[CBW * 17];
    int tid = threadIdx.x;
    for (int q = tid; q < CBW * 17; q += 256) tile[q] = 0.f;
    int b = blockIdx.x;
    int start = cbptr[b], end = cbptr[b + 1];
    int slot = tid >> 4;          // 16 quarter-wave edge slots
    int f = tid & 15;
    __syncthreads();
    int i = start + slot;
    for (; i + 16 < end; i += 32) {
        int p0 = pk[i], p1 = pk[i + 16];
        float v0 = bf2f(y2b[(size_t)(p0 >> 7) * 16 + f]);
        float v1 = bf2f(y2b[(size_t)(p1 >> 7) * 16 + f]);
        atomicAdd(&tile[(p0 & 127) * 17 + f], v0);
        atomicAdd(&tile[(p1 & 127) * 17 + f], v1);
    }
    for (; i < end; i += 16) {
        int p = pk[i];
        atomicAdd(&tile[(p & 127) * 17 + f], bf2f(y2b[(size_t)(p >> 7) * 16 + f]));
    }
    __syncthreads();
    int nmax = NN - b * CBW; if (nmax > CBW) nmax = CBW;
    if (tid < nmax) {
        int g = b * CBW + tid;
        float dc = dis[g];
        const float* hs = hw0 + (size_t)g * NCLS;
        float val[NCLS];
#pragma unroll
        for (int j = 0; j < NCLS; ++j) val[j] = hs[j] - dc * tile[tid * 17 + j];
        float m = val[0];
#pragma unroll
        for (int j = 1; j < NCLS; ++j) m = fmaxf(m, val[j]);
        float s = 0.f;
#pragma unroll
        for (int j = 0; j < NCLS; ++j) s += expf(val[j] - m);
        float lse = m + logf(s);
#pragma unroll
        for (int j = 0; j < NCLS; ++j) tile[tid * 17 + j] = val[j] - lse;
    }
    __syncthreads();
    int total = nmax * NCLS;
    float* ob = out + (size_t)b * CBW * NCLS;
    for (int q = tid; q < total; q += 256)
        ob[q] = tile[(q / NCLS) * 17 + q % NCLS];
}

// ---------------------------------------------------------------------------
extern "C" void kernel_launch(void* const* d_in, const int* in_sizes, int n_in,
                              void* d_out, int out_size, void* d_ws, size_t ws_size,
                              hipStream_t stream) {
    const float* x    = (const float*)d_in[0];
    const int*   ei   = (const int*)d_in[1];
    const float* W0_1 = (const float*)d_in[2];
    const float* W1_1 = (const float*)d_in[3];
    const float* b1   = (const float*)d_in[4];
    const float* W0_2 = (const float*)d_in[5];
    const float* W1_2 = (const float*)d_in[6];
    const float* b2   = (const float*)d_in[7];

    const int E = in_sizes[1] / 2;
    const int* row = ei;
    const int* col = ei + E;

    // workspace (ints; every segment 16B-aligned):
    float* dis   = (float*)d_ws;                        // NN (+16 pad)
    int* cbptr   = (int*)d_ws + 100016;                 // NBC+1 (+pad) -> 800
    int* rbptr   = cbptr + 800;                         // NBR+1 (+pad) -> 400
    int* ctot    = rbptr + 400;                         // 800
    int* rtot    = ctot + 800;                          // 400
    int* ghc     = rtot + 400;                          // NBC*HB = 400384
    int* ghr     = ghc + NBC * HB;                      // NBR*HB = 200192
    int* pk      = ghr + NBR * HB;                      // E
    unsigned char* rkb = (unsigned char*)(pk + E);      // E bytes
    float* xw0   = (float*)(pk + E + E / 4);            // NN*HID
    unsigned* y1b = (unsigned*)(xw0 + (size_t)NN * HID);// NN*16
    float* hw0   = (float*)(y1b + (size_t)NN * 16);     // NN*NCLS
    unsigned* y2b = (unsigned*)(hw0 + (size_t)NN * NCLS);// NN*8

    // output: [log_softmax NN*NCLS][x_latent NN*HID]
    float* out_ls = (float*)d_out;
    float* h      = out_ls + (size_t)NN * NCLS;

    int chunk = (E + HB - 1) / HB;

    hist2_kernel<<<HB, 256, 0, stream>>>(row, col, ghc, ghr, E, chunk);
    coffs_kernel<<<NBC, 512, 0, stream>>>(ghc, ghr, ctot, rtot);
    bscan_kernel<<<1, 1024, 0, stream>>>(ctot, rtot, cbptr, rbptr);
    bucket2_kernel<<<HB, 256, 0, stream>>>(row, col, ghc, ghr, cbptr, rbptr,
                                           pk, rkb, E, chunk);
    countR_kernel<<<NBR, 256, 0, stream>>>(rkb, rbptr, dis);

    mm1_kernel<<<(NN + 255) / 256, 256, 0, stream>>>(x, dis, W0_1, W1_1, b1, xw0, y1b);
    fgH_kernel<<<NBC, 256, 0, stream>>>(pk, cbptr, (const unsigned short*)y1b,
                                        xw0, dis, h);
    mm2_kernel<<<(NN + 255) / 256, 256, 0, stream>>>(h, dis, W0_2, W1_2, b2, hw0, y2b);
    fgO_kernel<<<NBC, 256, 0, stream>>>(pk, cbptr, (const unsigned short*)y2b,
                                        hw0, dis, out_ls);
}

// Round 8
// 375.868 us; speedup vs baseline: 3.3298x; 3.3298x over previous
//
#include <hip/hip_runtime.h>

#define NN   100000
#define FIN  64
#define HID  32
#define NCLS 10
#define BW   256                    // destinations per bucket (both keys)
#define NB   391                    // ceil(NN/256)
#define HB   512                    // blocks in hist/bucket passes

__device__ __forceinline__ unsigned short f2bf(float x) {
    unsigned u = __float_as_uint(x);
    u = (u + 0x7FFFu + ((u >> 16) & 1u)) >> 16;   // round-to-nearest-even
    return (unsigned short)u;
}
__device__ __forceinline__ float bfLo(unsigned u) {
    return __uint_as_float(u << 16);
}
__device__ __forceinline__ float bfHi(unsigned u) {
    return __uint_as_float(u & 0xFFFF0000u);
}

// ---------------------------------------------------------------------------
// hist2: per-block LDS histograms of col-buckets and row-buckets (c>>8, r>>8).
// ghc/ghr layout [bucket][block]. No global atomics.
// ---------------------------------------------------------------------------
__global__ __launch_bounds__(256) void hist2_kernel(
        const int* __restrict__ row, const int* __restrict__ col,
        int* __restrict__ ghc, int* __restrict__ ghr, int E, int chunk) {
    __shared__ int lhc[NB], lhr[NB];
    for (int t = threadIdx.x; t < NB; t += 256) { lhc[t] = 0; lhr[t] = 0; }
    __syncthreads();
    int k = blockIdx.x;
    int base = k * chunk;
    int lim = base + chunk; if (lim > E) lim = E;
    for (int e = base + threadIdx.x; e < lim; e += 256) {
        int r = row[e], c = col[e];
        if (r != c) {
            atomicAdd(&lhc[c >> 8], 1);
            atomicAdd(&lhr[r >> 8], 1);
        }
    }
    __syncthreads();
    for (int t = threadIdx.x; t < NB; t += 256) {
        ghc[t * HB + k] = lhc[t];
        ghr[t * HB + k] = lhr[t];
    }
}

// ---------------------------------------------------------------------------
// coffs: per-bucket exclusive scan over the HB block-columns (in place) and
// per-bucket totals.
// ---------------------------------------------------------------------------
__global__ __launch_bounds__(512) void coffs_kernel(
        int* __restrict__ ghc, int* __restrict__ ghr,
        int* __restrict__ ctot, int* __restrict__ rtot) {
    __shared__ int sh[HB];
    int b = blockIdx.x, t = threadIdx.x;
    int v = ghc[b * HB + t];
    sh[t] = v;
    __syncthreads();
    for (int off = 1; off < HB; off <<= 1) {
        int u = (t >= off) ? sh[t - off] : 0;
        __syncthreads(); sh[t] += u; __syncthreads();
    }
    ghc[b * HB + t] = sh[t] - v;
    if (t == HB - 1) ctot[b] = sh[t];
    __syncthreads();
    int w = ghr[b * HB + t];
    sh[t] = w;
    __syncthreads();
    for (int off = 1; off < HB; off <<= 1) {
        int u = (t >= off) ? sh[t - off] : 0;
        __syncthreads(); sh[t] += u; __syncthreads();
    }
    ghr[b * HB + t] = sh[t] - w;
    if (t == HB - 1) rtot[b] = sh[t];
}

// ---------------------------------------------------------------------------
// bscan: exclusive scan of the NB bucket totals (both keys).
// ---------------------------------------------------------------------------
__global__ __launch_bounds__(512) void bscan_kernel(
        const int* __restrict__ ctot, const int* __restrict__ rtot,
        int* __restrict__ cbptr, int* __restrict__ rbptr) {
    __shared__ int sh[512];
    int t = threadIdx.x;
    int v = (t < NB) ? ctot[t] : 0;
    sh[t] = v;
    __syncthreads();
    for (int off = 1; off < 512; off <<= 1) {
        int u = (t >= off) ? sh[t - off] : 0;
        __syncthreads(); sh[t] += u; __syncthreads();
    }
    if (t < NB) cbptr[t] = sh[t] - v;
    if (t == NB - 1) cbptr[NB] = sh[t];
    __syncthreads();
    int w = (t < NB) ? rtot[t] : 0;
    sh[t] = w;
    __syncthreads();
    for (int off = 1; off < 512; off <<= 1) {
        int u = (t >= off) ? sh[t - off] : 0;
        __syncthreads(); sh[t] += u; __syncthreads();
    }
    if (t < NB) rbptr[t] = sh[t] - w;
    if (t == NB - 1) rbptr[NB] = sh[t];
}

// ---------------------------------------------------------------------------
// bucket2: deterministic bucketing (LDS cursors seeded from scans) — zero
// global atomics. Packed (r<<8)|(c&255) by col-bucket; byte (r&255) by row.
// ---------------------------------------------------------------------------
__global__ __launch_bounds__(256) void bucket2_kernel(
        const int* __restrict__ row, const int* __restrict__ col,
        const int* __restrict__ ghc, const int* __restrict__ ghr,
        const int* __restrict__ cbptr, const int* __restrict__ rbptr,
        int* __restrict__ pk, unsigned char* __restrict__ rkb,
        int E, int chunk) {
    __shared__ int lcc[NB], lcr[NB];
    int k = blockIdx.x;
    for (int t = threadIdx.x; t < NB; t += 256) {
        lcc[t] = cbptr[t] + ghc[t * HB + k];
        lcr[t] = rbptr[t] + ghr[t * HB + k];
    }
    __syncthreads();
    int base = k * chunk;
    int lim = base + chunk; if (lim > E) lim = E;
    for (int e = base + threadIdx.x; e < lim; e += 256) {
        int r = row[e], c = col[e];
        if (r != c) {
            int pc = atomicAdd(&lcc[c >> 8], 1);
            pk[pc] = (r << 8) | (c & 255);
            int pr = atomicAdd(&lcr[r >> 8], 1);
            rkb[pr] = (unsigned char)(r & 255);
        }
    }
}

// ---------------------------------------------------------------------------
// countR: per-row-bucket histogram of the byte stream -> dis[] directly.
// ---------------------------------------------------------------------------
__global__ __launch_bounds__(256) void countR_kernel(
        const unsigned char* __restrict__ rkb, const int* __restrict__ rbptr,
        float* __restrict__ dis) {
    __shared__ int cnt[BW];
    int b = blockIdx.x, t = threadIdx.x;
    cnt[t] = 0;
    __syncthreads();
    int s = rbptr[b], e = rbptr[b + 1];
    for (int i = s + t; i < e; i += 256) atomicAdd(&cnt[rkb[i]], 1);
    __syncthreads();
    int d = (b << 8) + t;
    if (d < NN) {
        int c = cnt[t];
        dis[d] = c > 0 ? rsqrtf((float)c) : 0.f;
    }
}

// ---------------------------------------------------------------------------
// place2: per-col-bucket LDS histogram + scan -> colptr; then place srow.
// ---------------------------------------------------------------------------
__global__ __launch_bounds__(256) void place2_kernel(
        const int* __restrict__ pk, const int* __restrict__ cbptr,
        int* __restrict__ colptr, int* __restrict__ srow) {
    __shared__ int lh[BW];
    __shared__ int incl[BW];
    __shared__ int lcur[BW];
    int b = blockIdx.x, t = threadIdx.x;
    int start = cbptr[b], end = cbptr[b + 1];
    lh[t] = 0;
    __syncthreads();
    for (int i = start + t; i < end; i += 256)
        atomicAdd(&lh[pk[i] & 255], 1);
    __syncthreads();
    int own = lh[t];
    incl[t] = own;
    __syncthreads();
    for (int off = 1; off < 256; off <<= 1) {
        int v = (t >= off) ? incl[t - off] : 0;
        __syncthreads(); incl[t] += v; __syncthreads();
    }
    int excl = start + incl[t] - own;
    int d = (b << 8) + t;
    if (d < NN) colptr[d] = excl;
    lcur[t] = excl;
    __syncthreads();
    for (int i = start + t; i < end; i += 256) {
        int p = pk[i];
        int pos = atomicAdd(&lcur[p & 255], 1);
        srow[pos] = p >> 8;
    }
    if (b == 0 && t == 0) colptr[NN] = cbptr[NB];
}

// ---------------------------------------------------------------------------
// mm1: xw0 = x @ W0_1 + b1 (fp32)  and  y1b = bf16(dis[n] * (x @ W1_1))
// ---------------------------------------------------------------------------
__global__ __launch_bounds__(256) void mm1_kernel(
        const float* __restrict__ x, const float* __restrict__ dis,
        const float* __restrict__ W0, const float* __restrict__ W1,
        const float* __restrict__ b1, float* __restrict__ xw0,
        unsigned* __restrict__ y1b) {
    int n = blockIdx.x * 256 + threadIdx.x;
    if (n >= NN) return;
    float acc0[HID], acc1[HID];
#pragma unroll
    for (int j = 0; j < HID; ++j) { acc0[j] = b1[j]; acc1[j] = 0.f; }
    const float4* xr = (const float4*)(x + (size_t)n * FIN);
    for (int k4 = 0; k4 < FIN / 4; ++k4) {
        float4 xv = xr[k4];
        float xs[4] = {xv.x, xv.y, xv.z, xv.w};
#pragma unroll
        for (int kk = 0; kk < 4; ++kk) {
            const float* w0r = W0 + (k4 * 4 + kk) * HID;
            const float* w1r = W1 + (k4 * 4 + kk) * HID;
#pragma unroll
            for (int j = 0; j < HID; ++j) {
                acc0[j] += xs[kk] * w0r[j];
                acc1[j] += xs[kk] * w1r[j];
            }
        }
    }
    float dn = dis[n];
    float4* d0 = (float4*)(xw0 + (size_t)n * HID);
#pragma unroll
    for (int j4 = 0; j4 < HID / 4; ++j4)
        d0[j4] = make_float4(acc0[j4*4], acc0[j4*4+1], acc0[j4*4+2], acc0[j4*4+3]);
    unsigned pw[16];
#pragma unroll
    for (int j2 = 0; j2 < 16; ++j2)
        pw[j2] = (unsigned)f2bf(dn * acc1[2*j2]) | ((unsigned)f2bf(dn * acc1[2*j2+1]) << 16);
    uint4* yd = (uint4*)(y1b + (size_t)n * 16);
#pragma unroll
    for (int q = 0; q < 4; ++q)
        yd[q] = make_uint4(pw[q*4], pw[q*4+1], pw[q*4+2], pw[q*4+3]);
}

// ---------------------------------------------------------------------------
// gatherH: h[c] = relu(xw0[c] - dis[c] * sum_{r in N(c)} y1[r]).
// One wave per node; 4 slots x 16 lanes; lane reads uint = 2 bf16 features;
// ILP2 -> 8 row-gathers in flight per wave; register accumulation.
// ---------------------------------------------------------------------------
__global__ __launch_bounds__(256) void gatherH_kernel(
        const int* __restrict__ colptr, const int* __restrict__ srow,
        const float* __restrict__ dis, const unsigned* __restrict__ y1b,
        const float* __restrict__ xw0, float* __restrict__ h) {
    int lane = threadIdx.x & 63;
    int sub = lane >> 4;          // 4 edge slots
    int f2 = lane & 15;           // feature pair
    int c = __builtin_amdgcn_readfirstlane(blockIdx.x * 4 + (threadIdx.x >> 6));
    if (c >= NN) return;
    int start = colptr[c], end = colptr[c + 1];
    float a0 = 0.f, a1 = 0.f, b0 = 0.f, b1 = 0.f;
    int i = start + sub;
    for (; i + 4 < end; i += 8) {
        unsigned u0 = y1b[(size_t)srow[i] * 16 + f2];
        unsigned u1 = y1b[(size_t)srow[i + 4] * 16 + f2];
        a0 += bfLo(u0); a1 += bfHi(u0);
        b0 += bfLo(u1); b1 += bfHi(u1);
    }
    for (; i < end; i += 4) {
        unsigned u = y1b[(size_t)srow[i] * 16 + f2];
        a0 += bfLo(u); a1 += bfHi(u);
    }
    a0 += b0; a1 += b1;
    a0 += __shfl_xor(a0, 16); a1 += __shfl_xor(a1, 16);
    a0 += __shfl_xor(a0, 32); a1 += __shfl_xor(a1, 32);
    if (lane < 16) {
        float dc = dis[c];
        const float2* xs = (const float2*)(xw0 + (size_t)c * HID + 2 * f2);
        float2 xv = xs[0];
        float2 o;
        o.x = fmaxf(xv.x - dc * a0, 0.f);
        o.y = fmaxf(xv.y - dc * a1, 0.f);
        *(float2*)(h + (size_t)c * HID + 2 * f2) = o;
    }
}

// ---------------------------------------------------------------------------
// mm2: hw0 = h @ W0_2 + b2 (fp32, [NN,10])  and  y2b = bf16(dis*(h @ W1_2))
// padded to 16 halfwords (8 uints).
// ---------------------------------------------------------------------------
__global__ __launch_bounds__(256) void mm2_kernel(
        const float* __restrict__ h, const float* __restrict__ dis,
        const float* __restrict__ W0, const float* __restrict__ W1,
        const float* __restrict__ b2, float* __restrict__ hw0,
        unsigned* __restrict__ y2b) {
    int n = blockIdx.x * 256 + threadIdx.x;
    if (n >= NN) return;
    float acc0[NCLS], acc1[NCLS];
#pragma unroll
    for (int j = 0; j < NCLS; ++j) { acc0[j] = b2[j]; acc1[j] = 0.f; }
    const float4* hr = (const float4*)(h + (size_t)n * HID);
#pragma unroll
    for (int k4 = 0; k4 < HID / 4; ++k4) {
        float4 hv = hr[k4];
        float hs[4] = {hv.x, hv.y, hv.z, hv.w};
#pragma unroll
        for (int kk = 0; kk < 4; ++kk) {
            const float* w0r = W0 + (k4 * 4 + kk) * NCLS;
            const float* w1r = W1 + (k4 * 4 + kk) * NCLS;
#pragma unroll
            for (int j = 0; j < NCLS; ++j) {
                acc0[j] += hs[kk] * w0r[j];
                acc1[j] += hs[kk] * w1r[j];
            }
        }
    }
    float dn = dis[n];
    float* hd = hw0 + (size_t)n * NCLS;
#pragma unroll
    for (int j = 0; j < NCLS; ++j) hd[j] = acc0[j];
    float v[16];
#pragma unroll
    for (int j = 0; j < NCLS; ++j) v[j] = dn * acc1[j];
#pragma unroll
    for (int j = NCLS; j < 16; ++j) v[j] = 0.f;
    unsigned pw[8];
#pragma unroll
    for (int j2 = 0; j2 < 8; ++j2)
        pw[j2] = (unsigned)f2bf(v[2*j2]) | ((unsigned)f2bf(v[2*j2+1]) << 16);
    uint4* yd = (uint4*)(y2b + (size_t)n * 8);
    yd[0] = make_uint4(pw[0], pw[1], pw[2], pw[3]);
    yd[1] = make_uint4(pw[4], pw[5], pw[6], pw[7]);
}

// ---------------------------------------------------------------------------
// gatherOut: out[c] = log_softmax(hw0[c] - dis[c]*sum y2[r]).
// One wave per node; 8 slots x 8 lanes (uint = 2 bf16); ILP2 -> 16 rows in
// flight; softmax across lanes 0-7 via shuffles.
// ---------------------------------------------------------------------------
__global__ __launch_bounds__(256) void gatherOut_kernel(
        const int* __restrict__ colptr, const int* __restrict__ srow,
        const float* __restrict__ dis, const unsigned* __restrict__ y2b,
        const float* __restrict__ hw0, float* __restrict__ out) {
    int lane = threadIdx.x & 63;
    int sub = lane >> 3;          // 8 edge slots
    int f2 = lane & 7;            // feature pair (of 16-wide padded row)
    int c = __builtin_amdgcn_readfirstlane(blockIdx.x * 4 + (threadIdx.x >> 6));
    if (c >= NN) return;
    int start = colptr[c], end = colptr[c + 1];
    float a0 = 0.f, a1 = 0.f, b0 = 0.f, b1 = 0.f;
    int i = start + sub;
    for (; i + 8 < end; i += 16) {
        unsigned u0 = y2b[(size_t)srow[i] * 8 + f2];
        unsigned u1 = y2b[(size_t)srow[i + 8] * 8 + f2];
        a0 += bfLo(u0); a1 += bfHi(u0);
        b0 += bfLo(u1); b1 += bfHi(u1);
    }
    for (; i < end; i += 8) {
        unsigned u = y2b[(size_t)srow[i] * 8 + f2];
        a0 += bfLo(u); a1 += bfHi(u);
    }
    a0 += b0; a1 += b1;
    a0 += __shfl_xor(a0, 8);  a1 += __shfl_xor(a1, 8);
    a0 += __shfl_xor(a0, 16); a1 += __shfl_xor(a1, 16);
    a0 += __shfl_xor(a0, 32); a1 += __shfl_xor(a1, 32);
    // lanes 0..7 hold totals for features (2*f2, 2*f2+1); classes are 0..9
    float dc = dis[c];
    int j0 = 2 * f2, j1 = 2 * f2 + 1;
    float v0 = (j0 < NCLS) ? hw0[(size_t)c * NCLS + j0] - dc * a0 : -INFINITY;
    float v1 = (j1 < NCLS) ? hw0[(size_t)c * NCLS + j1] - dc * a1 : -INFINITY;
    float m = fmaxf(v0, v1);
    m = fmaxf(m, __shfl_xor(m, 1));
    m = fmaxf(m, __shfl_xor(m, 2));
    m = fmaxf(m, __shfl_xor(m, 4));
    float s = ((j0 < NCLS) ? expf(v0 - m) : 0.f) + ((j1 < NCLS) ? expf(v1 - m) : 0.f);
    s += __shfl_xor(s, 1);
    s += __shfl_xor(s, 2);
    s += __shfl_xor(s, 4);
    float lse = m + logf(s);
    if (lane < 8) {
        if (j0 < NCLS) out[(size_t)c * NCLS + j0] = v0 - lse;
        if (j1 < NCLS) out[(size_t)c * NCLS + j1] = v1 - lse;
    }
}

// ---------------------------------------------------------------------------
extern "C" void kernel_launch(void* const* d_in, const int* in_sizes, int n_in,
                              void* d_out, int out_size, void* d_ws, size_t ws_size,
                              hipStream_t stream) {
    const float* x    = (const float*)d_in[0];
    const int*   ei   = (const int*)d_in[1];
    const float* W0_1 = (const float*)d_in[2];
    const float* W1_1 = (const float*)d_in[3];
    const float* b1   = (const float*)d_in[4];
    const float* W0_2 = (const float*)d_in[5];
    const float* W1_2 = (const float*)d_in[6];
    const float* b2   = (const float*)d_in[7];

    const int E = in_sizes[1] / 2;
    const int* row = ei;
    const int* col = ei + E;

    // workspace layout (ints; all segments 16B-aligned):
    // [colptr NN+8][dis NN][cbptr 512][rbptr 512][ctot 512][rtot 512][srow E]
    // region C (reused): phase1 = [ghc NB*HB][ghr NB*HB][pk E][rkb E bytes]
    //                    phase2 = [xw0 NN*32 f32][y1b NN*16 u32][hw0 NN*10 f32][y2b NN*8 u32]
    int*   colptr = (int*)d_ws;
    float* dis    = (float*)(colptr + NN + 8);
    int*   cbptr  = (int*)(dis + NN);
    int*   rbptr  = cbptr + 512;
    int*   ctot   = rbptr + 512;
    int*   rtot   = ctot + 512;
    int*   srow   = rtot + 512;
    int*   C      = srow + E;
    int*   ghc    = C;
    int*   ghr    = ghc + NB * HB;
    int*   pk     = ghr + NB * HB;
    unsigned char* rkb = (unsigned char*)(pk + E);
    float* xw0    = (float*)C;
    unsigned* y1b = (unsigned*)(xw0 + (size_t)NN * HID);
    float* hw0    = (float*)(y1b + (size_t)NN * 16);
    unsigned* y2b = (unsigned*)(hw0 + (size_t)NN * NCLS);

    // output: [log_softmax NN*NCLS][x_latent NN*HID]
    float* out_ls = (float*)d_out;
    float* h      = out_ls + (size_t)NN * NCLS;

    int chunk = (E + HB - 1) / HB;

    hist2_kernel<<<HB, 256, 0, stream>>>(row, col, ghc, ghr, E, chunk);
    coffs_kernel<<<NB, 512, 0, stream>>>(ghc, ghr, ctot, rtot);
    bscan_kernel<<<1, 512, 0, stream>>>(ctot, rtot, cbptr, rbptr);
    bucket2_kernel<<<HB, 256, 0, stream>>>(row, col, ghc, ghr, cbptr, rbptr,
                                           pk, rkb, E, chunk);
    countR_kernel<<<NB, 256, 0, stream>>>(rkb, rbptr, dis);
    place2_kernel<<<NB, 256, 0, stream>>>(pk, cbptr, colptr, srow);

    mm1_kernel<<<(NN + 255) / 256, 256, 0, stream>>>(x, dis, W0_1, W1_1, b1, xw0, y1b);
    gatherH_kernel<<<(NN + 3) / 4, 256, 0, stream>>>(colptr, srow, dis, y1b, xw0, h);
    mm2_kernel<<<(NN + 255) / 256, 256, 0, stream>>>(h, dis, W0_2, W1_2, b2, hw0, y2b);
    gatherOut_kernel<<<(NN + 3) / 4, 256, 0, stream>>>(colptr, srow, dis, y2b, hw0, out_ls);
}

// Round 9
// 346.193 us; speedup vs baseline: 3.6153x; 1.0857x over previous
//
#include <hip/hip_runtime.h>

#define NN   100000
#define FIN  64
#define HID  32
#define NCLS 10
#define BW   256                    // destinations per bucket (both keys)
#define NB   391                    // ceil(NN/256)
#define HB   128                    // chunks in hist/bucket passes

__device__ __forceinline__ unsigned short f2bf(float x) {
    unsigned u = __float_as_uint(x);
    u = (u + 0x7FFFu + ((u >> 16) & 1u)) >> 16;   // round-to-nearest-even
    return (unsigned short)u;
}
__device__ __forceinline__ float bfLo(unsigned u) {
    return __uint_as_float(u << 16);
}
__device__ __forceinline__ float bfHi(unsigned u) {
    return __uint_as_float(u & 0xFFFF0000u);
}
// chunk swizzle: adjacent chunks (adjacent output regions) on the same XCD
__device__ __forceinline__ int chunk_of(int b) {
    return ((b & 7) << 4) | (b >> 3);   // HB=128 = 8 XCDs x 16
}

// ---------------------------------------------------------------------------
// hist2: per-chunk LDS histograms of col-buckets and row-buckets (>>8).
// gh layout [chunk][bucket] (contiguous stores per block). No global atomics.
// ---------------------------------------------------------------------------
__global__ __launch_bounds__(256) void hist2_kernel(
        const int* __restrict__ row, const int* __restrict__ col,
        int* __restrict__ ghc, int* __restrict__ ghr, int E, int chunk, int vec) {
    __shared__ int lhc[NB], lhr[NB];
    for (int t = threadIdx.x; t < NB; t += 256) { lhc[t] = 0; lhr[t] = 0; }
    __syncthreads();
    int j = chunk_of(blockIdx.x);
    int base = j * chunk;
    int lim = base + chunk; if (lim > E) lim = E;
    if (vec) {
        for (int e = base + threadIdx.x * 4; e < lim; e += 1024) {
            int4 r4 = *(const int4*)(row + e);
            int4 c4 = *(const int4*)(col + e);
            if (r4.x != c4.x) { atomicAdd(&lhc[c4.x >> 8], 1); atomicAdd(&lhr[r4.x >> 8], 1); }
            if (r4.y != c4.y) { atomicAdd(&lhc[c4.y >> 8], 1); atomicAdd(&lhr[r4.y >> 8], 1); }
            if (r4.z != c4.z) { atomicAdd(&lhc[c4.z >> 8], 1); atomicAdd(&lhr[r4.z >> 8], 1); }
            if (r4.w != c4.w) { atomicAdd(&lhc[c4.w >> 8], 1); atomicAdd(&lhr[r4.w >> 8], 1); }
        }
    } else {
        for (int e = base + threadIdx.x; e < lim; e += 256) {
            int r = row[e], c = col[e];
            if (r != c) { atomicAdd(&lhc[c >> 8], 1); atomicAdd(&lhr[r >> 8], 1); }
        }
    }
    __syncthreads();
    for (int t = threadIdx.x; t < NB; t += 256) {
        ghc[j * NB + t] = lhc[t];
        ghr[j * NB + t] = lhr[t];
    }
}

// ---------------------------------------------------------------------------
// coffs: per-bucket exclusive scan over the HB chunk-entries (in place) and
// per-bucket totals. One block (128 threads) per bucket.
// ---------------------------------------------------------------------------
__global__ __launch_bounds__(HB) void coffs_kernel(
        int* __restrict__ ghc, int* __restrict__ ghr,
        int* __restrict__ ctot, int* __restrict__ rtot) {
    __shared__ int sh[HB];
    int b = blockIdx.x, t = threadIdx.x;
    int v = ghc[t * NB + b];
    sh[t] = v;
    __syncthreads();
    for (int off = 1; off < HB; off <<= 1) {
        int u = (t >= off) ? sh[t - off] : 0;
        __syncthreads(); sh[t] += u; __syncthreads();
    }
    ghc[t * NB + b] = sh[t] - v;
    if (t == HB - 1) ctot[b] = sh[t];
    __syncthreads();
    int w = ghr[t * NB + b];
    sh[t] = w;
    __syncthreads();
    for (int off = 1; off < HB; off <<= 1) {
        int u = (t >= off) ? sh[t - off] : 0;
        __syncthreads(); sh[t] += u; __syncthreads();
    }
    ghr[t * NB + b] = sh[t] - w;
    if (t == HB - 1) rtot[b] = sh[t];
}

// ---------------------------------------------------------------------------
// bscan: exclusive scan of the NB bucket totals (both keys).
// ---------------------------------------------------------------------------
__global__ __launch_bounds__(512) void bscan_kernel(
        const int* __restrict__ ctot, const int* __restrict__ rtot,
        int* __restrict__ cbptr, int* __restrict__ rbptr) {
    __shared__ int sh[512];
    int t = threadIdx.x;
    int v = (t < NB) ? ctot[t] : 0;
    sh[t] = v;
    __syncthreads();
    for (int off = 1; off < 512; off <<= 1) {
        int u = (t >= off) ? sh[t - off] : 0;
        __syncthreads(); sh[t] += u; __syncthreads();
    }
    if (t < NB) cbptr[t] = sh[t] - v;
    if (t == NB - 1) cbptr[NB] = sh[t];
    __syncthreads();
    int w = (t < NB) ? rtot[t] : 0;
    sh[t] = w;
    __syncthreads();
    for (int off = 1; off < 512; off <<= 1) {
        int u = (t >= off) ? sh[t - off] : 0;
        __syncthreads(); sh[t] += u; __syncthreads();
    }
    if (t < NB) rbptr[t] = sh[t] - w;
    if (t == NB - 1) rbptr[NB] = sh[t];
}

// ---------------------------------------------------------------------------
// bucket2: deterministic bucketing (LDS cursors seeded from scans) — zero
// global atomics. Packed (r<<8)|(c&255) by col-bucket; byte (r&255) by row.
// ---------------------------------------------------------------------------
__global__ __launch_bounds__(256) void bucket2_kernel(
        const int* __restrict__ row, const int* __restrict__ col,
        const int* __restrict__ ghc, const int* __restrict__ ghr,
        const int* __restrict__ cbptr, const int* __restrict__ rbptr,
        int* __restrict__ pk, unsigned char* __restrict__ rkb,
        int E, int chunk, int vec) {
    __shared__ int lcc[NB], lcr[NB];
    int j = chunk_of(blockIdx.x);
    for (int t = threadIdx.x; t < NB; t += 256) {
        lcc[t] = cbptr[t] + ghc[j * NB + t];
        lcr[t] = rbptr[t] + ghr[j * NB + t];
    }
    __syncthreads();
    int base = j * chunk;
    int lim = base + chunk; if (lim > E) lim = E;
    if (vec) {
        for (int e = base + threadIdx.x * 4; e < lim; e += 1024) {
            int4 r4 = *(const int4*)(row + e);
            int4 c4 = *(const int4*)(col + e);
            if (r4.x != c4.x) {
                int pc = atomicAdd(&lcc[c4.x >> 8], 1); pk[pc] = (r4.x << 8) | (c4.x & 255);
                int pr = atomicAdd(&lcr[r4.x >> 8], 1); rkb[pr] = (unsigned char)(r4.x & 255);
            }
            if (r4.y != c4.y) {
                int pc = atomicAdd(&lcc[c4.y >> 8], 1); pk[pc] = (r4.y << 8) | (c4.y & 255);
                int pr = atomicAdd(&lcr[r4.y >> 8], 1); rkb[pr] = (unsigned char)(r4.y & 255);
            }
            if (r4.z != c4.z) {
                int pc = atomicAdd(&lcc[c4.z >> 8], 1); pk[pc] = (r4.z << 8) | (c4.z & 255);
                int pr = atomicAdd(&lcr[r4.z >> 8], 1); rkb[pr] = (unsigned char)(r4.z & 255);
            }
            if (r4.w != c4.w) {
                int pc = atomicAdd(&lcc[c4.w >> 8], 1); pk[pc] = (r4.w << 8) | (c4.w & 255);
                int pr = atomicAdd(&lcr[r4.w >> 8], 1); rkb[pr] = (unsigned char)(r4.w & 255);
            }
        }
    } else {
        for (int e = base + threadIdx.x; e < lim; e += 256) {
            int r = row[e], c = col[e];
            if (r != c) {
                int pc = atomicAdd(&lcc[c >> 8], 1); pk[pc] = (r << 8) | (c & 255);
                int pr = atomicAdd(&lcr[r >> 8], 1); rkb[pr] = (unsigned char)(r & 255);
            }
        }
    }
}

// ---------------------------------------------------------------------------
// countR: per-row-bucket histogram of the byte stream -> dis[] directly.
// ---------------------------------------------------------------------------
__global__ __launch_bounds__(256) void countR_kernel(
        const unsigned char* __restrict__ rkb, const int* __restrict__ rbptr,
        float* __restrict__ dis) {
    __shared__ int cnt[BW];
    int b = blockIdx.x, t = threadIdx.x;
    cnt[t] = 0;
    __syncthreads();
    int s = rbptr[b], e = rbptr[b + 1];
    for (int i = s + t; i < e; i += 256) atomicAdd(&cnt[rkb[i]], 1);
    __syncthreads();
    int d = (b << 8) + t;
    if (d < NN) {
        int c = cnt[t];
        dis[d] = c > 0 ? rsqrtf((float)c) : 0.f;
    }
}

// ---------------------------------------------------------------------------
// place2: per-col-bucket LDS histogram + scan -> colptr; then place srow.
// ---------------------------------------------------------------------------
__global__ __launch_bounds__(256) void place2_kernel(
        const int* __restrict__ pk, const int* __restrict__ cbptr,
        int* __restrict__ colptr, int* __restrict__ srow) {
    __shared__ int lh[BW];
    __shared__ int incl[BW];
    __shared__ int lcur[BW];
    int b = blockIdx.x, t = threadIdx.x;
    int start = cbptr[b], end = cbptr[b + 1];
    lh[t] = 0;
    __syncthreads();
    for (int i = start + t; i < end; i += 256)
        atomicAdd(&lh[pk[i] & 255], 1);
    __syncthreads();
    int own = lh[t];
    incl[t] = own;
    __syncthreads();
    for (int off = 1; off < 256; off <<= 1) {
        int v = (t >= off) ? incl[t - off] : 0;
        __syncthreads(); incl[t] += v; __syncthreads();
    }
    int excl = start + incl[t] - own;
    int d = (b << 8) + t;
    if (d < NN) colptr[d] = excl;
    lcur[t] = excl;
    __syncthreads();
    for (int i = start + t; i < end; i += 256) {
        int p = pk[i];
        int pos = atomicAdd(&lcur[p & 255], 1);
        srow[pos] = p >> 8;
    }
    if (b == 0 && t == 0) colptr[NN] = cbptr[NB];
}

// ---------------------------------------------------------------------------
// mm1: xw0 = x @ W0_1 + b1 (fp32)  and  y1b = bf16(dis[n] * (x @ W1_1))
// ---------------------------------------------------------------------------
__global__ __launch_bounds__(256) void mm1_kernel(
        const float* __restrict__ x, const float* __restrict__ dis,
        const float* __restrict__ W0, const float* __restrict__ W1,
        const float* __restrict__ b1, float* __restrict__ xw0,
        unsigned* __restrict__ y1b) {
    int n = blockIdx.x * 256 + threadIdx.x;
    if (n >= NN) return;
    float acc0[HID], acc1[HID];
#pragma unroll
    for (int j = 0; j < HID; ++j) { acc0[j] = b1[j]; acc1[j] = 0.f; }
    const float4* xr = (const float4*)(x + (size_t)n * FIN);
    for (int k4 = 0; k4 < FIN / 4; ++k4) {
        float4 xv = xr[k4];
        float xs[4] = {xv.x, xv.y, xv.z, xv.w};
#pragma unroll
        for (int kk = 0; kk < 4; ++kk) {
            const float* w0r = W0 + (k4 * 4 + kk) * HID;
            const float* w1r = W1 + (k4 * 4 + kk) * HID;
#pragma unroll
            for (int j = 0; j < HID; ++j) {
                acc0[j] += xs[kk] * w0r[j];
                acc1[j] += xs[kk] * w1r[j];
            }
        }
    }
    float dn = dis[n];
    float4* d0 = (float4*)(xw0 + (size_t)n * HID);
#pragma unroll
    for (int j4 = 0; j4 < HID / 4; ++j4)
        d0[j4] = make_float4(acc0[j4*4], acc0[j4*4+1], acc0[j4*4+2], acc0[j4*4+3]);
    unsigned pw[16];
#pragma unroll
    for (int j2 = 0; j2 < 16; ++j2)
        pw[j2] = (unsigned)f2bf(dn * acc1[2*j2]) | ((unsigned)f2bf(dn * acc1[2*j2+1]) << 16);
    uint4* yd = (uint4*)(y1b + (size_t)n * 16);
#pragma unroll
    for (int q = 0; q < 4; ++q)
        yd[q] = make_uint4(pw[q*4], pw[q*4+1], pw[q*4+2], pw[q*4+3]);
}

// ---------------------------------------------------------------------------
// gatherH: h[c] = relu(xw0[c] - dis[c] * sum_{r in N(c)} y1[r]).
// One wave per node; 8 slots x 8 lanes x uint2 (= 4 bf16 features/lane);
// ILP2 -> 16 rows in flight per wave.
// ---------------------------------------------------------------------------
__global__ __launch_bounds__(256) void gatherH_kernel(
        const int* __restrict__ colptr, const int* __restrict__ srow,
        const float* __restrict__ dis, const unsigned* __restrict__ y1b,
        const float* __restrict__ xw0, float* __restrict__ h) {
    int lane = threadIdx.x & 63;
    int sub = lane >> 3;          // 8 edge slots
    int f4 = lane & 7;            // uint2 index (4 features)
    int c = __builtin_amdgcn_readfirstlane(blockIdx.x * 4 + (threadIdx.x >> 6));
    if (c >= NN) return;
    int start = colptr[c], end = colptr[c + 1];
    const uint2* Y = (const uint2*)y1b;
    float a0 = 0.f, a1 = 0.f, a2 = 0.f, a3 = 0.f;
    float b0 = 0.f, b1 = 0.f, b2 = 0.f, b3 = 0.f;
    int i = start + sub;
    for (; i + 8 < end; i += 16) {
        uint2 u = Y[(size_t)srow[i] * 8 + f4];
        uint2 v = Y[(size_t)srow[i + 8] * 8 + f4];
        a0 += bfLo(u.x); a1 += bfHi(u.x); a2 += bfLo(u.y); a3 += bfHi(u.y);
        b0 += bfLo(v.x); b1 += bfHi(v.x); b2 += bfLo(v.y); b3 += bfHi(v.y);
    }
    for (; i < end; i += 8) {
        uint2 u = Y[(size_t)srow[i] * 8 + f4];
        a0 += bfLo(u.x); a1 += bfHi(u.x); a2 += bfLo(u.y); a3 += bfHi(u.y);
    }
    a0 += b0; a1 += b1; a2 += b2; a3 += b3;
#pragma unroll
    for (int m = 8; m < 64; m <<= 1) {
        a0 += __shfl_xor(a0, m); a1 += __shfl_xor(a1, m);
        a2 += __shfl_xor(a2, m); a3 += __shfl_xor(a3, m);
    }
    if (lane < 8) {
        float dc = dis[c];
        float4 xv = *(const float4*)(xw0 + (size_t)c * HID + 4 * f4);
        float4 o;
        o.x = fmaxf(xv.x - dc * a0, 0.f);
        o.y = fmaxf(xv.y - dc * a1, 0.f);
        o.z = fmaxf(xv.z - dc * a2, 0.f);
        o.w = fmaxf(xv.w - dc * a3, 0.f);
        *(float4*)(h + (size_t)c * HID + 4 * f4) = o;
    }
}

// ---------------------------------------------------------------------------
// mm2: hw0 = h @ W0_2 + b2 (fp32, [NN,10])  and  y2b = bf16(dis*(h @ W1_2))
// padded to 16 halfwords (8 uints).
// ---------------------------------------------------------------------------
__global__ __launch_bounds__(256) void mm2_kernel(
        const float* __restrict__ h, const float* __restrict__ dis,
        const float* __restrict__ W0, const float* __restrict__ W1,
        const float* __restrict__ b2, float* __restrict__ hw0,
        unsigned* __restrict__ y2b) {
    int n = blockIdx.x * 256 + threadIdx.x;
    if (n >= NN) return;
    float acc0[NCLS], acc1[NCLS];
#pragma unroll
    for (int j = 0; j < NCLS; ++j) { acc0[j] = b2[j]; acc1[j] = 0.f; }
    const float4* hr = (const float4*)(h + (size_t)n * HID);
#pragma unroll
    for (int k4 = 0; k4 < HID / 4; ++k4) {
        float4 hv = hr[k4];
        float hs[4] = {hv.x, hv.y, hv.z, hv.w};
#pragma unroll
        for (int kk = 0; kk < 4; ++kk) {
            const float* w0r = W0 + (k4 * 4 + kk) * NCLS;
            const float* w1r = W1 + (k4 * 4 + kk) * NCLS;
#pragma unroll
            for (int j = 0; j < NCLS; ++j) {
                acc0[j] += hs[kk] * w0r[j];
                acc1[j] += hs[kk] * w1r[j];
            }
        }
    }
    float dn = dis[n];
    float* hd = hw0 + (size_t)n * NCLS;
#pragma unroll
    for (int j = 0; j < NCLS; ++j) hd[j] = acc0[j];
    float v[16];
#pragma unroll
    for (int j = 0; j < NCLS; ++j) v[j] = dn * acc1[j];
#pragma unroll
    for (int j = NCLS; j < 16; ++j) v[j] = 0.f;
    unsigned pw[8];
#pragma unroll
    for (int j2 = 0; j2 < 8; ++j2)
        pw[j2] = (unsigned)f2bf(v[2*j2]) | ((unsigned)f2bf(v[2*j2+1]) << 16);
    uint4* yd = (uint4*)(y2b + (size_t)n * 8);
    yd[0] = make_uint4(pw[0], pw[1], pw[2], pw[3]);
    yd[1] = make_uint4(pw[4], pw[5], pw[6], pw[7]);
}

// ---------------------------------------------------------------------------
// gatherOut: out[c] = log_softmax(hw0[c] - dis[c]*sum y2[r]).
// One wave per node; 16 slots x 4 lanes x uint2; ILP2 -> 32 rows in flight.
// ---------------------------------------------------------------------------
__global__ __launch_bounds__(256) void gatherOut_kernel(
        const int* __restrict__ colptr, const int* __restrict__ srow,
        const float* __restrict__ dis, const unsigned* __restrict__ y2b,
        const float* __restrict__ hw0, float* __restrict__ out) {
    int lane = threadIdx.x & 63;
    int sub = lane >> 2;          // 16 edge slots
    int f4 = lane & 3;            // uint2 index (4 features of padded 16)
    int c = __builtin_amdgcn_readfirstlane(blockIdx.x * 4 + (threadIdx.x >> 6));
    if (c >= NN) return;
    int start = colptr[c], end = colptr[c + 1];
    const uint2* Y = (const uint2*)y2b;
    float a0 = 0.f, a1 = 0.f, a2 = 0.f, a3 = 0.f;
    float b0 = 0.f, b1 = 0.f, b2 = 0.f, b3 = 0.f;
    int i = start + sub;
    for (; i + 16 < end; i += 32) {
        uint2 u = Y[(size_t)srow[i] * 4 + f4];
        uint2 v = Y[(size_t)srow[i + 16] * 4 + f4];
        a0 += bfLo(u.x); a1 += bfHi(u.x); a2 += bfLo(u.y); a3 += bfHi(u.y);
        b0 += bfLo(v.x); b1 += bfHi(v.x); b2 += bfLo(v.y); b3 += bfHi(v.y);
    }
    for (; i < end; i += 16) {
        uint2 u = Y[(size_t)srow[i] * 4 + f4];
        a0 += bfLo(u.x); a1 += bfHi(u.x); a2 += bfLo(u.y); a3 += bfHi(u.y);
    }
    a0 += b0; a1 += b1; a2 += b2; a3 += b3;
#pragma unroll
    for (int m = 4; m < 64; m <<= 1) {
        a0 += __shfl_xor(a0, m); a1 += __shfl_xor(a1, m);
        a2 += __shfl_xor(a2, m); a3 += __shfl_xor(a3, m);
    }
    // lanes 0..3 hold features 4*f4 .. 4*f4+3 (classes 0..9 of padded 16)
    float dc = dis[c];
    int j0 = 4 * f4;
    float vv[4] = {a0, a1, a2, a3};
    float val[4];
#pragma unroll
    for (int jj = 0; jj < 4; ++jj) {
        int j = j0 + jj;
        val[jj] = (j < NCLS) ? hw0[(size_t)c * NCLS + j] - dc * vv[jj] : -INFINITY;
    }
    float m = fmaxf(fmaxf(val[0], val[1]), fmaxf(val[2], val[3]));
    m = fmaxf(m, __shfl_xor(m, 1));
    m = fmaxf(m, __shfl_xor(m, 2));
    float s = 0.f;
#pragma unroll
    for (int jj = 0; jj < 4; ++jj)
        if (j0 + jj < NCLS) s += expf(val[jj] - m);
    s += __shfl_xor(s, 1);
    s += __shfl_xor(s, 2);
    float lse = m + logf(s);
    if (lane < 4) {
#pragma unroll
        for (int jj = 0; jj < 4; ++jj) {
            int j = j0 + jj;
            if (j < NCLS) out[(size_t)c * NCLS + j] = val[jj] - lse;
        }
    }
}

// ---------------------------------------------------------------------------
extern "C" void kernel_launch(void* const* d_in, const int* in_sizes, int n_in,
                              void* d_out, int out_size, void* d_ws, size_t ws_size,
                              hipStream_t stream) {
    const float* x    = (const float*)d_in[0];
    const int*   ei   = (const int*)d_in[1];
    const float* W0_1 = (const float*)d_in[2];
    const float* W1_1 = (const float*)d_in[3];
    const float* b1   = (const float*)d_in[4];
    const float* W0_2 = (const float*)d_in[5];
    const float* W1_2 = (const float*)d_in[6];
    const float* b2   = (const float*)d_in[7];

    const int E = in_sizes[1] / 2;
    const int* row = ei;
    const int* col = ei + E;

    // workspace layout (int offsets; every segment 16B-aligned):
    // [colptr NN+16][dis NN][cbptr 512][rbptr 512][ctot 512][rtot 512][srow E]
    // region C: phase1 = [ghc NB*HB][ghr NB*HB][pk E][rkb E bytes]
    //           phase2 = [xw0 NN*32 f32][y1b NN*16 u32][hw0 NN*10 f32][y2b NN*8 u32]
    int*   colptr = (int*)d_ws;
    float* dis    = (float*)(colptr + NN + 16);
    int*   cbptr  = (int*)(dis + NN);
    int*   rbptr  = cbptr + 512;
    int*   ctot   = rbptr + 512;
    int*   rtot   = ctot + 512;
    int*   srow   = rtot + 512;
    int*   C      = srow + E;
    int*   ghc    = C;
    int*   ghr    = ghc + NB * HB;
    int*   pk     = ghr + NB * HB;
    unsigned char* rkb = (unsigned char*)(pk + E);
    float* xw0    = (float*)C;
    unsigned* y1b = (unsigned*)(xw0 + (size_t)NN * HID);
    float* hw0    = (float*)(y1b + (size_t)NN * 16);
    unsigned* y2b = (unsigned*)(hw0 + (size_t)NN * NCLS);

    // output: [log_softmax NN*NCLS][x_latent NN*HID]
    float* out_ls = (float*)d_out;
    float* h      = out_ls + (size_t)NN * NCLS;

    int chunk = (E + HB - 1) / HB;
    int vec = ((E & 3) == 0 && (chunk & 3) == 0) ? 1 : 0;

    hist2_kernel<<<HB, 256, 0, stream>>>(row, col, ghc, ghr, E, chunk, vec);
    coffs_kernel<<<NB, HB, 0, stream>>>(ghc, ghr, ctot, rtot);
    bscan_kernel<<<1, 512, 0, stream>>>(ctot, rtot, cbptr, rbptr);
    bucket2_kernel<<<HB, 256, 0, stream>>>(row, col, ghc, ghr, cbptr, rbptr,
                                           pk, rkb, E, chunk, vec);
    countR_kernel<<<NB, 256, 0, stream>>>(rkb, rbptr, dis);
    place2_kernel<<<NB, 256, 0, stream>>>(pk, cbptr, colptr, srow);

    mm1_kernel<<<(NN + 255) / 256, 256, 0, stream>>>(x, dis, W0_1, W1_1, b1, xw0, y1b);
    gatherH_kernel<<<(NN + 3) / 4, 256, 0, stream>>>(colptr, srow, dis, y1b, xw0, h);
    mm2_kernel<<<(NN + 255) / 256, 256, 0, stream>>>(h, dis, W0_2, W1_2, b2, hw0, y2b);
    gatherOut_kernel<<<(NN + 3) / 4, 256, 0, stream>>>(colptr, srow, dis, y2b, hw0, out_ls);
}